// Round 9
// baseline (277.490 us; speedup 1.0000x reference)
//
#include <hip/hip_runtime.h>

#define NH 128
#define NW 128
#define ND 128
#define HWD (NH * NW * ND)
#define NWD (NW * ND)
#define NB 2

typedef float f32x2 __attribute__((ext_vector_type(2)));
typedef float f32x4 __attribute__((ext_vector_type(4)));

#define SB() __builtin_amdgcn_sched_barrier(0)
#define LD2(dst, voff, base) asm volatile("global_load_dwordx2 %0, %1, %2" : "=v"(dst) : "v"(voff), "s"(base))
#define TOUCH(x) asm volatile("" : "+v"(x))

__device__ __forceinline__ void newton4(float U[3][3]) {
#pragma unroll
    for (int it = 0; it < 4; ++it) {
        float c00 = U[1][1]*U[2][2] - U[1][2]*U[2][1];
        float c01 = U[0][2]*U[2][1] - U[0][1]*U[2][2];
        float c02 = U[0][1]*U[1][2] - U[0][2]*U[1][1];
        float c10 = U[1][2]*U[2][0] - U[1][0]*U[2][2];
        float c11 = U[0][0]*U[2][2] - U[0][2]*U[2][0];
        float c12 = U[0][2]*U[1][0] - U[0][0]*U[1][2];
        float c20 = U[1][0]*U[2][1] - U[1][1]*U[2][0];
        float c21 = U[0][1]*U[2][0] - U[0][0]*U[2][1];
        float c22 = U[0][0]*U[1][1] - U[0][1]*U[1][0];
        float det = U[0][0]*c00 + U[0][1]*c10 + U[0][2]*c20;

        float l    = __log2f(fabsf(det));                               // v_log_f32
        float zeta = __builtin_amdgcn_exp2f(-0.33333333333333333f * l); // v_exp_f32
        float s    = copysignf(zeta * zeta, det);
        float hz = 0.5f * zeta;
        float hs = 0.5f * s;

        float n00 = hz*U[0][0] + c00*hs;
        float n01 = hz*U[0][1] + c10*hs;
        float n02 = hz*U[0][2] + c20*hs;
        float n10 = hz*U[1][0] + c01*hs;
        float n11 = hz*U[1][1] + c11*hs;
        float n12 = hz*U[1][2] + c21*hs;
        float n20 = hz*U[2][0] + c02*hs;
        float n21 = hz*U[2][1] + c12*hs;
        float n22 = hz*U[2][2] + c22*hs;
        U[0][0]=n00; U[0][1]=n01; U[0][2]=n02;
        U[1][0]=n10; U[1][1]=n11; U[1][2]=n12;
        U[2][0]=n20; U[2][1]=n21; U[2][2]=n22;
    }
}

__global__ __launch_bounds__(256) void warp_dti_kernel(
    const float* __restrict__ dti,
    const float* __restrict__ ddf,
    float* __restrict__ out)
{
    // 4 voxels/thread along d (d0..d0+3, 16B-aligned). 4096 blocks x 256 threads.
    // XCD-chunked bijective swizzle: 4096 = 8 XCDs x 512.
    const int blk0 = blockIdx.x;
    const int blk  = ((blk0 & 7) << 9) | (blk0 >> 3);

    const int b   = blk >> 11;                 // scalar
    const int h   = (blk >> 4) & 127;          // scalar
    const int wg  = blk & 15;                  // scalar
    const int tid = threadIdx.x;
    const int w   = (wg << 3) | (tid >> 5);    // 2 values per wave
    const int d0  = (tid & 31) << 2;           // per-lane, 16B-aligned
    const int sp0 = (h << 14) | (w << 7) | d0;

    const float* dch[3];
    const float* tch[6];
#pragma unroll
    for (int c = 0; c < 3; ++c) dch[c] = ddf + (size_t)(b * 3 + c) * HWD;
#pragma unroll
    for (int c = 0; c < 6; ++c) tch[c] = dti + (size_t)(b * 6 + c) * HWD;

    const int ohm = (h > 0)      ? -NWD : 0;
    const int ohp = (h < NH - 1) ?  NWD : 0;
    const int owm = (w > 0)      ? -ND  : 0;
    const int owp = (w < NW - 1) ?  ND  : 0;
    const float sh = (h > 0 && h < NH - 1) ? 0.5f : 1.0f;
    const float sw = (w > 0 && w < NW - 1) ? 0.5f : 1.0f;

    // ---- ddf: 7 loads per channel for 4 voxels (21 total, was 84) ----
    f32x4 ce[3], hm4[3], hp4[3], wm4[3], wp4[3];
    float dmv[3], dpv[3];
#pragma unroll
    for (int c = 0; c < 3; ++c) {
        ce[c]  = *reinterpret_cast<const f32x4*>(dch[c] + sp0);          // d0..d0+3
        hm4[c] = *reinterpret_cast<const f32x4*>(dch[c] + sp0 + ohm);
        hp4[c] = *reinterpret_cast<const f32x4*>(dch[c] + sp0 + ohp);
        wm4[c] = *reinterpret_cast<const f32x4*>(dch[c] + sp0 + owm);
        wp4[c] = *reinterpret_cast<const f32x4*>(dch[c] + sp0 + owp);
        dmv[c] = dch[c][sp0 + ((d0 > 0)        ? -1 : 0)];  // unused if d0==0
        dpv[c] = dch[c][sp0 + ((d0 < ND - 4)   ?  4 : 3)];  // unused if d0==124
    }

    // ---- per-voxel Jacobians + coords (all in registers; d-grad shares the quad) ----
    float U[4][3][3];
    float cxv[4], cyv[4], czv[4];
#pragma unroll
    for (int v = 0; v < 4; ++v) {
#pragma unroll
        for (int c = 0; c < 3; ++c) {
            float gd;
            if (v == 0)      gd = (d0 > 0)      ? 0.5f*(ce[c].y - dmv[c]) : (ce[c].y - ce[c].x);
            else if (v == 1) gd = 0.5f*(ce[c].z - ce[c].x);
            else if (v == 2) gd = 0.5f*(ce[c].w - ce[c].y);
            else             gd = (d0 < ND - 4) ? 0.5f*(dpv[c] - ce[c].z) : (ce[c].w - ce[c].z);
            U[v][c][0] = sh * (hp4[c][v] - hm4[c][v]);
            U[v][c][1] = sw * (wp4[c][v] - wm4[c][v]);
            U[v][c][2] = gd;
        }
        U[v][0][0] += 1.0f; U[v][1][1] += 1.0f; U[v][2][2] += 1.0f;
        cxv[v] = (float)h        + ce[0][v];
        cyv[v] = (float)w        + ce[1][v];
        czv[v] = (float)(d0 + v) + ce[2][v];
    }

    f32x4 Tq[6];

    // ---- per-voxel: corner setup, asm gathers, Newton in shadow, accumulate, sandwich ----
#pragma unroll
    for (int v = 0; v < 4; ++v) {
        const float cx = cxv[v], cy = cyv[v], cz = czv[v];
        const float flx = floorf(cx), fly = floorf(cy), flz = floorf(cz);
        const float fx = cx - flx, fy = cy - fly, fz = cz - flz;
        const int x0 = (int)flx, y0 = (int)fly, z0 = (int)flz;
        const int xa = min(max(x0,     0), NH - 1), xb = min(max(x0 + 1, 0), NH - 1);
        const int ya = min(max(y0,     0), NW - 1), yb = min(max(y0 + 1, 0), NW - 1);
        const int pa = min(max(z0, 0), ND - 2);   // z-pair base; clamp folded into weights

        unsigned voffs[4];
        voffs[0] = (unsigned)(((xa * NW + ya) * ND) + pa) * 4u;
        voffs[1] = (unsigned)(((xa * NW + yb) * ND) + pa) * 4u;
        voffs[2] = (unsigned)(((xb * NW + ya) * ND) + pa) * 4u;
        voffs[3] = (unsigned)(((xb * NW + yb) * ND) + pa) * 4u;

        SB();
        f32x2 g[6][4];
#pragma unroll
        for (int ch = 0; ch < 6; ++ch)
#pragma unroll
            for (int c = 0; c < 4; ++c)
                LD2(g[ch][c], voffs[c], tch[ch]);
        SB();

        // Newton (4 iters, R8-validated) in the gather latency shadow
        newton4(U[v]);

        // corner weights (still in the shadow)
        const float wza = 1.0f - fz, wzb = fz;
        const float wv0 = ((z0 <= ND - 2) ? wza : 0.0f) + ((z0 <= -1) ? wzb : 0.0f);
        const float wv1 = ((z0 >= ND - 1) ? wza : 0.0f) + ((z0 >=  0) ? wzb : 0.0f);
        const float wxa = 1.0f - fx, wya = 1.0f - fy;
        float wxy[4];
        wxy[0] = wxa * wya;  wxy[1] = wxa * fy;
        wxy[2] = fx  * wya;  wxy[3] = fx  * fy;
        float wA[4], wB[4];
#pragma unroll
        for (int c = 0; c < 4; ++c) { wA[c] = wxy[c] * wv0; wB[c] = wxy[c] * wv1; }

        asm volatile("s_waitcnt vmcnt(0)" ::: "memory");
        SB();
#pragma unroll
        for (int ch = 0; ch < 6; ++ch)
#pragma unroll
            for (int c = 0; c < 4; ++c) TOUCH(g[ch][c]);

        float acc[6] = {0.f, 0.f, 0.f, 0.f, 0.f, 0.f};
#pragma unroll
        for (int c = 0; c < 4; ++c)
#pragma unroll
            for (int ch = 0; ch < 6; ++ch)
                acc[ch] = fmaf(wA[c], g[ch][c].x, fmaf(wB[c], g[ch][c].y, acc[ch]));

        // T = R^T D R for this voxel
        float Dm00 = acc[0], Dm01 = acc[1], Dm02 = acc[3];
        float Dm11 = acc[2], Dm12 = acc[4], Dm22 = acc[5];
        float M[3][3];
#pragma unroll
        for (int i = 0; i < 3; ++i) {
            M[i][0] = U[v][0][i]*Dm00 + U[v][1][i]*Dm01 + U[v][2][i]*Dm02;
            M[i][1] = U[v][0][i]*Dm01 + U[v][1][i]*Dm11 + U[v][2][i]*Dm12;
            M[i][2] = U[v][0][i]*Dm02 + U[v][1][i]*Dm12 + U[v][2][i]*Dm22;
        }
        Tq[0][v] = M[0][0]*U[v][0][0] + M[0][1]*U[v][1][0] + M[0][2]*U[v][2][0];
        Tq[1][v] = M[1][0]*U[v][0][0] + M[1][1]*U[v][1][0] + M[1][2]*U[v][2][0];
        Tq[2][v] = M[1][0]*U[v][0][1] + M[1][1]*U[v][1][1] + M[1][2]*U[v][2][1];
        Tq[3][v] = M[2][0]*U[v][0][0] + M[2][1]*U[v][1][0] + M[2][2]*U[v][2][0];
        Tq[4][v] = M[2][0]*U[v][0][1] + M[2][1]*U[v][1][1] + M[2][2]*U[v][2][1];
        Tq[5][v] = M[2][0]*U[v][0][2] + M[2][1]*U[v][1][2] + M[2][2]*U[v][2][2];
    }

    // ---- stores: 6 x dwordx4 (16B-aligned), was 24 scalar ----
    float* obase = out + (size_t)b * 6 * HWD + sp0;
#pragma unroll
    for (int ch = 0; ch < 6; ++ch)
        *reinterpret_cast<f32x4*>(obase + (size_t)ch * HWD) = Tq[ch];
}

extern "C" void kernel_launch(void* const* d_in, const int* in_sizes, int n_in,
                              void* d_out, int out_size, void* d_ws, size_t ws_size,
                              hipStream_t stream) {
    const float* dti = (const float*)d_in[0];
    const float* ddf = (const float*)d_in[1];
    float* o = (float*)d_out;
    const int nblocks = NB * HWD / (256 * 4);   // 4096 blocks, 4 voxels/thread
    warp_dti_kernel<<<nblocks, 256, 0, stream>>>(dti, ddf, o);
}